// Round 19
// baseline (390.977 us; speedup 1.0000x reference)
//
#include <hip/hip_runtime.h>
#include <hip/hip_fp16.h>

#define BATCH 32
#define TLEN  4096
#define CH    128      // C == F == 128
#define KW    3
#define DIL   8

#define BM    128                // output rows per block
#define HR    (BM + 2 * DIL)     // 144  h rows needed
#define WROWS (BM + 4 * DIL)     // 160  x rows needed
#define LDSC  132                // 264B stride ≡ 2 (mod 32 dwords): ~2-way free.

typedef _Float16 f16x8 __attribute__((ext_vector_type(8)));
typedef float    f32x4 __attribute__((ext_vector_type(4)));

// ---------------------------------------------------------------------------
// Prep: Wt[j][f][c] = (f16) W[c][j][f]
// ---------------------------------------------------------------------------
__global__ void prep_weights_kernel(const float* __restrict__ W1,
                                    const float* __restrict__ W2,
                                    _Float16* __restrict__ Wt1,
                                    _Float16* __restrict__ Wt2) {
    const int total = KW * CH * CH;
    int idx = blockIdx.x * 256 + threadIdx.x;
    if (idx >= 2 * total) return;
    const float* W  = (idx < total) ? W1 : W2;
    _Float16*    Wt = (idx < total) ? Wt1 : Wt2;
    int r = idx % total;
    int j = r / (CH * CH);
    int f = (r / CH) % CH;
    int c = r % CH;
    Wt[j * CH * CH + f * CH + c] = (_Float16)W[c * (KW * CH) + j * CH + f];
}

// ---------------------------------------------------------------------------
// ABLATION round 2 (r18 found: stage = only ~5us; GEMM-vs-store unresolved
// because top-5 crowds out all but the slowest kernel).
//   VAR=0 REPS=2: real kernel, runs LAST, computes the answer twice ->
//                 correct output AND ~140us so it lands in top-5 by name.
//   VAR=2 REPS=4: both GEMM loops skipped (w/hs kept live, rule 17) ->
//                 4x scaled so it lands in top-5 by name.
//   VAR=3 REPS=2: epilogue computed, not stored -> inferred via
//                 total - prep - D(V2) - D(V0).
// ---------------------------------------------------------------------------
template<int VAR, int REPS>
__global__ __launch_bounds__(256)
void fused_deconv_kernel(const float* __restrict__ x,
                         const _Float16* __restrict__ Wt1,
                         const float* __restrict__ bias1,
                         const _Float16* __restrict__ Wt2,
                         const float* __restrict__ bias2,
                         float* __restrict__ out)
{
    __shared__ __align__(16) _Float16 xs[WROWS][LDSC];   // 42240 B
    __shared__ __align__(16) _Float16 hs[HR][LDSC];      // 38016 B

    const int tid  = threadIdx.x;
    const int lane = tid & 63;
    const int wid  = tid >> 6;         // 0..3
    const int l15  = lane & 15;
    const int kg   = lane >> 4;        // 0..3
    const int nc   = wid << 5;         // wave column base: 0,32,64,96

    const int bt0 = blockIdx.x;
    const int bt  = (bt0 & 7) * 128 + (bt0 >> 3);   // XCD-bijective swizzle
    const int b   = bt >> 5;
    const int t0  = (bt & 31) << 7;

    const float bv1_0 = 128.0f * bias1[nc + l15];
    const float bv1_1 = 128.0f * bias1[nc + 16 + l15];
    const float bv2_0 = 128.0f * bias2[nc + l15];
    const float bv2_1 = 128.0f * bias2[nc + 16 + l15];

#pragma unroll 1
    for (int rep = 0; rep < REPS; ++rep) {

        // ---- w1 prefetch (24 x 16B); in flight over stage
        f16x8 w1[12][2];
#pragma unroll
        for (int ks = 0; ks < 12; ++ks) {
            const int j  = ks >> 2;
            const int c0 = (ks & 3) << 5;
            const _Float16* wb = Wt1 + (size_t)j * (CH * CH) + c0 + kg * 8;
            w1[ks][0] = *(const f16x8*)(wb + (nc + l15) * CH);
            w1[ks][1] = *(const f16x8*)(wb + (nc + 16 + l15) * CH);
        }
        if constexpr (VAR == 2) {
#pragma unroll
            for (int ks = 0; ks < 12; ++ks)
                asm volatile("" :: "v"(w1[ks][0]), "v"(w1[ks][1]));
        }

        // ---- stage x window
#pragma unroll
        for (int p = 0; p < 10; ++p) {
            const int i   = tid + 256 * p;
            const int row = i >> 4;
            const int c8  = (i & 15) << 3;
            const int t   = t0 + row;
            f16x8 o;
            if (t < TLEN) {
                const float* xp = x + ((size_t)b * TLEN + t) * CH + c8;
                f32x4 v0 = *(const f32x4*)(xp + 0);
                f32x4 v1 = *(const f32x4*)(xp + 4);
                o[0] = (_Float16)v0[0]; o[1] = (_Float16)v0[1];
                o[2] = (_Float16)v0[2]; o[3] = (_Float16)v0[3];
                o[4] = (_Float16)v1[0]; o[5] = (_Float16)v1[1];
                o[6] = (_Float16)v1[2]; o[7] = (_Float16)v1[3];
            } else {
                o = (f16x8){};
            }
            *(f16x8*)&xs[row][c8] = o;
        }

        __syncthreads();   // barrier 1: xs published

        // ---- GEMM1 (skipped in VAR=2)
        f32x4 acc1[9][2];
#pragma unroll
        for (int m = 0; m < 9; ++m) {
            acc1[m][0] = (f32x4){0.f, 0.f, 0.f, 0.f};
            acc1[m][1] = (f32x4){0.f, 0.f, 0.f, 0.f};
        }
        if constexpr (VAR != 2) {
#pragma unroll
            for (int ks = 0; ks < 12; ++ks) {
                const int j     = ks >> 2;
                const int c0    = (ks & 3) << 5;
                const int shift = (2 - j) * DIL;
#pragma unroll
                for (int m = 0; m < 9; ++m) {
                    f16x8 af = *(const f16x8*)&xs[m * 16 + shift + l15][c0 + kg * 8];
                    acc1[m][0] = __builtin_amdgcn_mfma_f32_16x16x32_f16(af, w1[ks][0], acc1[m][0], 0, 0, 0);
                    acc1[m][1] = __builtin_amdgcn_mfma_f32_16x16x32_f16(af, w1[ks][1], acc1[m][1], 0, 0, 0);
                }
            }
        }

        // ---- w2 prefetch; in flight over h-store
        f16x8 w2[12][2];
#pragma unroll
        for (int ks = 0; ks < 12; ++ks) {
            const int j  = ks >> 2;
            const int c0 = (ks & 3) << 5;
            const _Float16* wb = Wt2 + (size_t)j * (CH * CH) + c0 + kg * 8;
            w2[ks][0] = *(const f16x8*)(wb + (nc + l15) * CH);
            w2[ks][1] = *(const f16x8*)(wb + (nc + 16 + l15) * CH);
        }
        if constexpr (VAR == 2) {
#pragma unroll
            for (int ks = 0; ks < 12; ++ks)
                asm volatile("" :: "v"(w2[ks][0]), "v"(w2[ks][1]));
        }

        // ---- h-store
#pragma unroll
        for (int m = 0; m < 9; ++m) {
#pragma unroll
            for (int nn = 0; nn < 2; ++nn) {
                const float bv = nn ? bv1_1 : bv1_0;
                const int f = nc + nn * 16 + l15;
#pragma unroll
                for (int i = 0; i < 4; ++i) {
                    const int r = m * 16 + kg * 4 + i;
                    const int u = t0 + r;
                    const int nv = 1 + (u < TLEN - DIL) + (u < TLEN - 2 * DIL);
                    float v = acc1[m][nn][i] + (float)nv * bv;
                    v = fmaxf(v, 0.0f);
                    hs[r][f] = (u < TLEN) ? (_Float16)v : (_Float16)0.0f;
                }
            }
        }
        __syncthreads();   // barrier 2: hs published

        if constexpr (VAR == 2) {
            volatile const _Float16* hp = &hs[0][0];
            float kk = (float)hp[(tid * 131) % (HR * LDSC)];
            asm volatile("" :: "v"(kk));
        }

        // ---- GEMM2 (skipped in VAR=2)
        f32x4 acc2[8][2];
#pragma unroll
        for (int m = 0; m < 8; ++m) {
            acc2[m][0] = (f32x4){0.f, 0.f, 0.f, 0.f};
            acc2[m][1] = (f32x4){0.f, 0.f, 0.f, 0.f};
        }
        if constexpr (VAR != 2) {
#pragma unroll
            for (int ks = 0; ks < 12; ++ks) {
                const int j     = ks >> 2;
                const int c0    = (ks & 3) << 5;
                const int shift = (2 - j) * DIL;
#pragma unroll
                for (int m = 0; m < 8; ++m) {
                    f16x8 af = *(const f16x8*)&hs[m * 16 + shift + l15][c0 + kg * 8];
                    acc2[m][0] = __builtin_amdgcn_mfma_f32_16x16x32_f16(af, w2[ks][0], acc2[m][0], 0, 0, 0);
                    acc2[m][1] = __builtin_amdgcn_mfma_f32_16x16x32_f16(af, w2[ks][1], acc2[m][1], 0, 0, 0);
                }
            }
        }

        // ---- epilogue (VAR=3: computed, kept live, not stored)
#pragma unroll
        for (int m = 0; m < 8; ++m) {
#pragma unroll
            for (int nn = 0; nn < 2; ++nn) {
                const float bv = nn ? bv2_1 : bv2_0;
                const int f = nc + nn * 16 + l15;
#pragma unroll
                for (int i = 0; i < 4; ++i) {
                    const int r = m * 16 + kg * 4 + i;
                    const int t = t0 + r;
                    const int nv = 1 + (t < TLEN - DIL) + (t < TLEN - 2 * DIL);
                    float v = acc2[m][nn][i] + (float)nv * bv;
                    v = fmaxf(v, 0.0f);
                    v = fmaxf(v + (float)xs[r][f], 0.0f);
                    if constexpr (VAR == 3) {
                        asm volatile("" :: "v"(v));
                    } else {
                        out[((size_t)b * TLEN + t) * CH + f] = v;
                    }
                }
            }
        }

        if (rep + 1 < REPS) __syncthreads();   // xs reused next rep
    }
}

// ---------------------------------------------------------------------------
extern "C" void kernel_launch(void* const* d_in, const int* in_sizes, int n_in,
                              void* d_out, int out_size, void* d_ws, size_t ws_size,
                              hipStream_t stream) {
    const float* x  = (const float*)d_in[0];
    const float* W1 = (const float*)d_in[1];
    const float* b1 = (const float*)d_in[2];
    const float* W2 = (const float*)d_in[3];
    const float* b2 = (const float*)d_in[4];
    float* out = (float*)d_out;

    _Float16* Wt1 = (_Float16*)d_ws;
    _Float16* Wt2 = Wt1 + KW * CH * CH;

    prep_weights_kernel<<<(2 * KW * CH * CH + 255) / 256, 256, 0, stream>>>(W1, W2, Wt1, Wt2);

    const int grid = BATCH * (TLEN / BM);   // 1024 blocks

    // Probes (output overwritten by the real VAR=0 below):
    fused_deconv_kernel<2, 4><<<grid, 256, 0, stream>>>(x, Wt1, b1, Wt2, b2, out);  // no-GEMM, x4
    fused_deconv_kernel<3, 2><<<grid, 256, 0, stream>>>(x, Wt1, b1, Wt2, b2, out);  // no-store, x2

    // Real kernel — last, REPS=2 (computes the correct answer twice so it
    // lands in the top-5 table for a same-build baseline).
    fused_deconv_kernel<0, 2><<<grid, 256, 0, stream>>>(x, Wt1, b1, Wt2, b2, out);
}

// Round 20
// 64.841 us; speedup vs baseline: 6.0298x; 6.0298x over previous
//
#include <hip/hip_runtime.h>
#include <hip/hip_fp16.h>

#define BATCH 32
#define TLEN  4096
#define CH    128      // C == F == 128
#define KW    3
#define DIL   8

#define BM    128                // output rows per block
#define HR    (BM + 2 * DIL)     // 144  h rows needed
#define WROWS (BM + 4 * DIL)     // 160  x rows needed
#define LDSC  132                // 264B stride ≡ 2 (mod 32 dwords): ~2-way free.
                                 // 136 (≡4) gave 8-way conflicts (r6-r11).

typedef _Float16 f16x8  __attribute__((ext_vector_type(8)));
typedef float    f32x4  __attribute__((ext_vector_type(4)));
typedef float    f32x16 __attribute__((ext_vector_type(16)));

// ---------------------------------------------------------------------------
// Prep: Wt[j][f][c] = (f16) W[c][j][f]
// ---------------------------------------------------------------------------
__global__ void prep_weights_kernel(const float* __restrict__ W1,
                                    const float* __restrict__ W2,
                                    _Float16* __restrict__ Wt1,
                                    _Float16* __restrict__ Wt2) {
    const int total = KW * CH * CH;
    int idx = blockIdx.x * 256 + threadIdx.x;
    if (idx >= 2 * total) return;
    const float* W  = (idx < total) ? W1 : W2;
    _Float16*    Wt = (idx < total) ? Wt1 : Wt2;
    int r = idx % total;
    int j = r / (CH * CH);
    int f = (r / CH) % CH;
    int c = r % CH;
    Wt[j * CH * CH + f * CH + c] = (_Float16)W[c * (KW * CH) + j * CH + f];
}

// ---------------------------------------------------------------------------
// Fused TemporalDeConvBlock — 32x32x16 MFMA build (r14 structure otherwise).
// r18/r19 ablations: stage ~5us, GEMM phases ~75% of wall time with pipes
// ~15% busy -> phases serialize; the largest serial term is GEMM-phase LDS
// wave-instructions. 32x32 MFMA halves A-fragment reads (408->216/wave) and
// trims MFMA issue (408->216 instr).
// Layouts (m74/m101-verified): A row=l&31,k=(l>>5)*8+e; B col=l&31 same k;
// D col=l&31, row=(r&3)+8*(r>>2)+4*(l>>5), r in [0,16).
// 256 thr = 4 waves; wave w owns cols [32w,32w+32). K = 3 taps x 128 c =
// 24 steps of 16. G1 row-tile 4 is partial: OOB A-rows clamped to 159,
// garbage masked at h-store (only regs r<8 -> rows 128..143).
// LESSONS: caps below live-set spill (r3/r5); 512-thr pinned to 64 VGPR
// (r4/r6/r7); occupancy/barriers/conflicts/L2/instr-count/staging/ring-
// prefetch all non-binding (r8-r17). WRITE~65MB = no-spill invariant.
// ---------------------------------------------------------------------------
__global__ __launch_bounds__(256)
void fused_deconv_kernel(const float* __restrict__ x,
                         const _Float16* __restrict__ Wt1,
                         const float* __restrict__ bias1,
                         const _Float16* __restrict__ Wt2,
                         const float* __restrict__ bias2,
                         float* __restrict__ out)
{
    __shared__ __align__(16) _Float16 xs[WROWS][LDSC];   // 42240 B
    __shared__ __align__(16) _Float16 hs[HR][LDSC];      // 38016 B

    const int tid  = threadIdx.x;
    const int lane = tid & 63;
    const int wid  = tid >> 6;         // 0..3
    const int l31  = lane & 31;
    const int hg   = lane >> 5;        // 0..1 (K half-group)
    const int hg8  = hg << 3;
    const int nc   = wid << 5;         // wave column base: 0,32,64,96

    // XCD-aware bijective swizzle: grid 1024 = 8 XCDs x 128 chunks.
    const int bt0 = blockIdx.x;
    const int bt  = (bt0 & 7) * 128 + (bt0 >> 3);
    const int b   = bt >> 5;
    const int t0  = (bt & 31) << 7;

    // ---- prefetch GEMM1 weight fragments: 24 steps x 16B = 96 VGPRs.
    // B-frag: col f = nc + l31, k = cb + hg*8 + e.
    f16x8 w1[24];
#pragma unroll
    for (int s = 0; s < 24; ++s) {
        const int j  = s >> 3;
        const int cb = (s & 7) << 4;
        w1[s] = *(const f16x8*)(Wt1 + (size_t)j * (CH * CH)
                                + (nc + l31) * CH + cb + hg8);
    }

    // ---- stage x window (f32 -> f16), rows t0..t0+159, zero past TLEN.
#pragma unroll
    for (int p = 0; p < 10; ++p) {
        const int i   = tid + 256 * p;
        const int row = i >> 4;
        const int c8  = (i & 15) << 3;
        const int t   = t0 + row;
        f16x8 o;
        if (t < TLEN) {
            const float* xp = x + ((size_t)b * TLEN + t) * CH + c8;
            f32x4 v0 = *(const f32x4*)(xp + 0);
            f32x4 v1 = *(const f32x4*)(xp + 4);
            o[0] = (_Float16)v0[0]; o[1] = (_Float16)v0[1];
            o[2] = (_Float16)v0[2]; o[3] = (_Float16)v0[3];
            o[4] = (_Float16)v1[0]; o[5] = (_Float16)v1[1];
            o[6] = (_Float16)v1[2]; o[7] = (_Float16)v1[3];
        } else {
            o = (f16x8){};
        }
        *(f16x8*)&xs[row][c8] = o;
    }

    const float bv1 = 128.0f * bias1[nc + l31];   // per-lane scalar (col fixed)
    const float bv2 = 128.0f * bias2[nc + l31];

    __syncthreads();   // barrier 1: xs published

    // ---- GEMM1: h rows 0..143 (5 row-tiles of 32, tile 4 partial),
    // cols [nc,nc+32) — 120 MFMA / 120 ds_read per wave.
    f32x16 acc1[5];
#pragma unroll
    for (int rt = 0; rt < 5; ++rt) acc1[rt] = (f32x16){};
#pragma unroll
    for (int s = 0; s < 24; ++s) {
        const int j     = s >> 3;
        const int cb    = (s & 7) << 4;
        const int shift = (2 - j) * DIL;
#pragma unroll
        for (int rt = 0; rt < 5; ++rt) {
            int row = rt * 32 + l31 + shift;
            if (rt == 4) row = (row > 159) ? 159 : row;   // clamp garbage lanes
            f16x8 af = *(const f16x8*)&xs[row][cb + hg8];
            acc1[rt] = __builtin_amdgcn_mfma_f32_32x32x16_f16(af, w1[s], acc1[rt], 0, 0, 0);
        }
    }

    // ---- prefetch GEMM2 weights (w1 dead, regs recycle)
    f16x8 w2[24];
#pragma unroll
    for (int s = 0; s < 24; ++s) {
        const int j  = s >> 3;
        const int cb = (s & 7) << 4;
        w2[s] = *(const f16x8*)(Wt2 + (size_t)j * (CH * CH)
                                + (nc + l31) * CH + cb + hg8);
    }

    // ---- h-store: D col = nc+l31, row = rt*32 + (r&3)+8*(r>>2)+4*hg
#pragma unroll
    for (int rt = 0; rt < 5; ++rt) {
#pragma unroll
        for (int r = 0; r < 16; ++r) {
            if (rt == 4 && r >= 8) continue;     // rows >=144 don't exist
            const int row = rt * 32 + (r & 3) + 8 * (r >> 2) + 4 * hg;
            const int u   = t0 + row;
            const int nv  = 1 + (u < TLEN - DIL) + (u < TLEN - 2 * DIL);
            float v = acc1[rt][r] + (float)nv * bv1;
            v = fmaxf(v, 0.0f);
            hs[row][nc + l31] = (u < TLEN) ? (_Float16)v : (_Float16)0.0f;
        }
    }
    __syncthreads();   // barrier 2: hs published

    // ---- GEMM2: out rows 0..127 (4 row-tiles), cols [nc,nc+32)
    // — 96 MFMA / 96 ds_read per wave. A-rows <= 96+31+16 = 143 (in range).
    f32x16 acc2[4];
#pragma unroll
    for (int rt = 0; rt < 4; ++rt) acc2[rt] = (f32x16){};
#pragma unroll
    for (int s = 0; s < 24; ++s) {
        const int j     = s >> 3;
        const int cb    = (s & 7) << 4;
        const int shift = (2 - j) * DIL;
#pragma unroll
        for (int rt = 0; rt < 4; ++rt) {
            const int row = rt * 32 + l31 + shift;
            f16x8 af = *(const f16x8*)&hs[row][cb + hg8];
            acc2[rt] = __builtin_amdgcn_mfma_f32_32x32x16_f16(af, w2[s], acc2[rt], 0, 0, 0);
        }
    }

    // ---- epilogue: bias2 + relu, + residual (f16 from live xs), relu, store
#pragma unroll
    for (int rt = 0; rt < 4; ++rt) {
#pragma unroll
        for (int r = 0; r < 16; ++r) {
            const int row = rt * 32 + (r & 3) + 8 * (r >> 2) + 4 * hg;
            const int t   = t0 + row;
            const int nv  = 1 + (t < TLEN - DIL) + (t < TLEN - 2 * DIL);
            float v = acc2[rt][r] + (float)nv * bv2;
            v = fmaxf(v, 0.0f);
            v = fmaxf(v + (float)xs[row][nc + l31], 0.0f);
            out[((size_t)b * TLEN + t) * CH + nc + l31] = v;
        }
    }
}

// ---------------------------------------------------------------------------
extern "C" void kernel_launch(void* const* d_in, const int* in_sizes, int n_in,
                              void* d_out, int out_size, void* d_ws, size_t ws_size,
                              hipStream_t stream) {
    const float* x  = (const float*)d_in[0];
    const float* W1 = (const float*)d_in[1];
    const float* b1 = (const float*)d_in[2];
    const float* W2 = (const float*)d_in[3];
    const float* b2 = (const float*)d_in[4];
    float* out = (float*)d_out;

    _Float16* Wt1 = (_Float16*)d_ws;
    _Float16* Wt2 = Wt1 + KW * CH * CH;

    prep_weights_kernel<<<(2 * KW * CH * CH + 255) / 256, 256, 0, stream>>>(W1, W2, Wt1, Wt2);

    const int grid = BATCH * (TLEN / BM);   // 1024 blocks (= 8 XCDs x 128)
    fused_deconv_kernel<<<grid, 256, 0, stream>>>(x, Wt1, b1, Wt2, b2, out);
}